// Round 1
// baseline (248.585 us; speedup 1.0000x reference)
//
#include <hip/hip_runtime.h>

// R9: (1) XOR-swizzled global_load_lds staging in BOTH gemm128 and flash
// (ks2/vsT/lA/lB row stride = 32 banks -> 16-way conflict on every b128 frag
// read; 2.29e7 conflict cycles = ~37us of flash's 90us). Swizzle: global col
// c16^(row&7) -> LDS slot c16; banks become f(col16) only -> 2-way (free).
// (2) flash K/V double-buffered with ONE barrier per round: DMA for kt+1
// issued at top of round kt, drained by the NEXT round's barrier (full round
// in flight, unlike m97's issue->drain shape). LDS 59.8KB.
// R10: identical resubmit — previous round failed with GPUAcquisitionTimeout
// (no data). Capturing baseline counters on this session's machine.

typedef unsigned short u16;
typedef __attribute__((ext_vector_type(8))) __bf16 bf16x8;
typedef __attribute__((ext_vector_type(4))) float f32x4;
typedef __attribute__((address_space(1))) const unsigned int gu32;
typedef __attribute__((address_space(3))) unsigned int lu32;

#define LOG2E 1.4426950408889634f

__device__ __forceinline__ float b2f(u16 u) {
    unsigned int i = ((unsigned int)u) << 16;
    float f; __builtin_memcpy(&f, &i, 4); return f;
}
__device__ __forceinline__ u16 f2b(float f) {
    unsigned int x; __builtin_memcpy(&x, &f, 4);
    x += 0x7fffu + ((x >> 16) & 1u);   // RTNE
    return (u16)(x >> 16);
}

#define LDT 72

// ---------------------------------------------------------------------------
__global__ void detect_dtype(const u16* __restrict__ x, int* __restrict__ flag)
{
    if (threadIdx.x == 0 && blockIdx.x == 0) {
        float mx = 0.f;
        for (int i = 0; i < 128; i++) {
            float v = fabsf(b2f(x[i]));
            if (!(v <= 1e30f)) v = 1e30f;
            mx = fmaxf(mx, v);
        }
        *flag = (mx > 1e4f) ? 1 : 0;
    }
}

struct CvtArgs {
    const void* src[7];
    u16*        dst[7];
    int         n[7];
    float       sc[7];
};

__global__ __launch_bounds__(256) void convert_all(CvtArgs a, const int* __restrict__ flag)
{
    const int fl = *flag;
    const int g = blockIdx.x * 256 + threadIdx.x;
    const int stride = gridDim.x * 256;
    #pragma unroll 1
    for (int s = 0; s < 7; s++) {
        const int n = a.n[s];
        const float sc = a.sc[s];
        const float* fs = (const float*)a.src[s];
        const u16*  hs = (const u16*)a.src[s];
        u16* d = a.dst[s];
        for (int i = g; i < n; i += stride) {
            float v = fl ? fs[i] : b2f(hs[i]);
            d[i] = f2b(v * sc);
        }
    }
}

// ---------------------------------------------------------------------------
// 128x128 GEMM (TN), BK=64, swizzled global_load_lds staging.
// EPI=0: proj (dual-dtype store). EPI=1: qkv (rope/scale; LDS-staged stores;
// V -> [bn][kt][d][l64] tile-contiguous).
// ---------------------------------------------------------------------------
template <int EPI>
__global__ __launch_bounds__(256) void gemm128(
    const u16* __restrict__ A, const u16* __restrict__ Bw,
    const u16* __restrict__ bias, void* __restrict__ Cout,
    const int* __restrict__ flag, u16* __restrict__ qkvT, int N, int K)
{
    __shared__ __align__(16) u16 smem[16384];    // lA|lB; reused as ct[128][128]
    u16* lA = smem;
    u16* lB = smem + 8192;
    u16* ct = smem;
    const int tid = threadIdx.x;
    const int m0 = blockIdx.x * 128, n0 = blockIdx.y * 128;
    const int wave = tid >> 6, lane = tid & 63;
    const int wm = (wave & 1) * 64, wn = (wave >> 1) * 64;
    const int lm = lane & 15, lq = lane >> 4;
    const int srow = lane >> 3;
    const int sgcol = ((lane & 7) ^ (srow & 7)) * 8;       // swizzled global col
    const int sw0 = (lq ^ (lm & 7)) * 8;                   // frag col, group lq
    const int sw1 = ((lq + 4) ^ (lm & 7)) * 8;             // frag col, group lq+4
    f32x4 acc[4][4] = {};
    for (int k0 = 0; k0 < K; k0 += 64) {
        if (k0) __syncthreads();
        #pragma unroll
        for (int c4 = 0; c4 < 4; c4++) {
            const int c = wave * 4 + c4;
            const int row = c * 8 + srow;
            __builtin_amdgcn_global_load_lds(
                (gu32*)(A + (size_t)(m0 + row) * K + k0 + sgcol),
                (lu32*)&lA[c * 512], 16, 0, 0);
            __builtin_amdgcn_global_load_lds(
                (gu32*)(Bw + (size_t)(n0 + row) * K + k0 + sgcol),
                (lu32*)&lB[c * 512], 16, 0, 0);
        }
        __syncthreads();
        #pragma unroll
        for (int ks = 0; ks < 64; ks += 32) {
            const int sw = ks ? sw1 : sw0;
            bf16x8 af[4], bfr[4];
            #pragma unroll
            for (int i = 0; i < 4; i++) af[i]  = *(const bf16x8*)&lA[(wm + i * 16 + lm) * 64 + sw];
            #pragma unroll
            for (int j = 0; j < 4; j++) bfr[j] = *(const bf16x8*)&lB[(wn + j * 16 + lm) * 64 + sw];
            #pragma unroll
            for (int i = 0; i < 4; i++)
                #pragma unroll
                for (int j = 0; j < 4; j++)
                    acc[i][j] = __builtin_amdgcn_mfma_f32_16x16x32_bf16(af[i], bfr[j], acc[i][j], 0, 0, 0);
        }
    }
    if (EPI == 0) {
        const int fl = *flag;
        #pragma unroll
        for (int j = 0; j < 4; j++) {
            const int n = n0 + wn + j * 16 + lm;
            const float bj = b2f(bias[n]);
            #pragma unroll
            for (int i = 0; i < 4; i++)
                #pragma unroll
                for (int r = 0; r < 4; r++) {
                    const int m = m0 + wm + i * 16 + lq * 4 + r;
                    const float v = acc[i][j][r] + bj;
                    if (fl) ((float*)Cout)[(size_t)m * 768 + n] = v;
                    else    ((u16*)Cout)[(size_t)m * 768 + n] = f2b(v);
                }
        }
    } else {
        const int which = n0 / 768;
        const bool vt = (which == 2);
        __syncthreads();
        #pragma unroll
        for (int j = 0; j < 4; j++) {
            const int nl = wn + j * 16 + lm;
            const int n = n0 + nl;
            const float bj = b2f(bias[n]);
            #pragma unroll
            for (int i = 0; i < 4; i++)
                #pragma unroll
                for (int r = 0; r < 4; r++) {
                    const int ml = wm + i * 16 + lq * 4 + r;
                    const int m = m0 + ml;
                    float v = acc[i][j][r] + bj;
                    const float p = __shfl_xor(v, 1);
                    const int l = m & 1023, d = n & 63;
                    float o = v;
                    if (which < 2) {
                        const int pi = d >> 1, jj = pi & 15;
                        const float coord = (pi < 16) ? (float)(l & 31) : (float)(l >> 5);
                        const float ang = coord * __expf(-(float)jj * 0.5756462732485115f);
                        float sn, cs; __sincosf(ang, &sn, &cs);
                        o = v * cs + ((d & 1) ? p * sn : -(p * sn));
                        if (which == 1) o *= 0.125f * LOG2E;
                    }
                    ct[vt ? nl * 128 + ml : ml * 128 + nl] = f2b(o);
                }
        }
        __syncthreads();
        const size_t HL = (size_t)96 * 1024 * 64;
        const int nh0 = (n0 >> 6) % 12, bb = m0 >> 10, l0 = m0 & 1023;
        if (!vt) {
            #pragma unroll
            for (int pass = 0; pass < 8; pass++) {
                const int chunk = pass * 256 + tid;
                const int run = chunk >> 3, lc = chunk & 7;
                const int ml = run >> 1, h = run & 1;
                u16* gp = qkvT + (size_t)which * HL
                        + ((size_t)(bb * 12 + nh0 + h) * 1024 + l0 + ml) * 64 + lc * 8;
                *(uint4*)gp = *(const uint4*)&ct[ml * 128 + h * 64 + lc * 8];
            }
        } else {
            const int kt0 = l0 >> 6;
            #pragma unroll
            for (int pass = 0; pass < 8; pass++) {
                const int run = pass * 16 + (tid >> 4);
                const int ln = tid & 15;
                const int half = ln >> 3, l8 = ln & 7;
                u16* gp = qkvT + 2 * HL
                        + (size_t)(bb * 12 + nh0 + (run >> 6)) * 65536
                        + (size_t)(kt0 + half) * 4096 + (run & 63) * 64 + l8 * 8;
                *(uint4*)gp = *(const uint4*)&ct[run * 128 + ln * 8];
            }
        }
    }
}

// ---------------------------------------------------------------------------
// K2: MFMA flash attention. Swizzled DMA staging + double-buffered K/V with
// one barrier per round (DMA for kt+1 in flight during round kt's compute).
// ---------------------------------------------------------------------------
__global__ __launch_bounds__(256) void flash_attn_mfma(
    const u16* __restrict__ qkvT, const u16* __restrict__ relH,
    const u16* __restrict__ relW, u16* __restrict__ outb)
{
    __shared__ __align__(16) u16 ks2[2 * 4096];    // [buf][64][64] swizzled
    __shared__ __align__(16) u16 vsT[2 * 4096];    // [buf][64][64] swizzled
    __shared__ __align__(16) u16 qs[64 * LDT];     // Q tile; aliased as pT
    __shared__ __align__(16) u16 Th[64 * LDT];
    __shared__ __align__(16) u16 Tw[64 * LDT];
    u16* rel = vsT;                                // prologue staging (buf0, unswizzled)
    u16* pT  = qs;

    const int tid = threadIdx.x;
    const int bn = blockIdx.x, q0 = blockIdx.y * 64;
    const size_t HL = (size_t)96 * 1024 * 64;
    const u16* qg  = qkvT + (size_t)bn * 65536 + (size_t)q0 * 64;
    const u16* kgb = qkvT + HL + (size_t)bn * 65536;
    const u16* vgb = qkvT + 2 * HL + (size_t)bn * 65536;   // [kt][d][l64]

    for (int g = tid; g < 1024; g += 256) {
        int r = g >> 4, c = (g & 15) * 4;
        *(ushort4*)&qs[r * LDT + c] = ((const ushort4*)qg)[g];
    }
    for (int g = tid; g < 1008; g += 256) {
        int r = g >> 4, c = (g & 15) * 4;
        *(ushort4*)&rel[r * 64 + c] = *(const ushort4*)(relH + g * 4);
    }
    if (tid < 16) { ushort4 z = {0, 0, 0, 0}; *(ushort4*)&rel[63 * 64 + tid * 4] = z; }
    __syncthreads();

    const int w = tid >> 6, lane = tid & 63;
    const int lm = lane & 15, lq = lane >> 4;

    const bf16x8 bq0 = *(const bf16x8*)&qs[(w * 16 + lm) * LDT + lq * 8];
    const bf16x8 bq1 = *(const bf16x8*)&qs[(w * 16 + lm) * LDT + 32 + lq * 8];

    {   // Th = Q . relH^T   (rel unswizzled; prologue-only conflicts are negligible)
        f32x4 tacc[4] = {};
        #pragma unroll
        for (int nb = 0; nb < 4; nb++) {
            bf16x8 r0 = *(const bf16x8*)&rel[(nb * 16 + lm) * 64 + lq * 8];
            bf16x8 r1 = *(const bf16x8*)&rel[(nb * 16 + lm) * 64 + 32 + lq * 8];
            tacc[nb] = __builtin_amdgcn_mfma_f32_16x16x32_bf16(bq0, r0, tacc[nb], 0, 0, 0);
            tacc[nb] = __builtin_amdgcn_mfma_f32_16x16x32_bf16(bq1, r1, tacc[nb], 0, 0, 0);
        }
        #pragma unroll
        for (int nb = 0; nb < 4; nb++)
            #pragma unroll
            for (int rr = 0; rr < 4; rr++)
                Th[(w * 16 + lq * 4 + rr) * LDT + nb * 16 + lm] = f2b(tacc[nb][rr]);
    }
    __syncthreads();
    for (int g = tid; g < 1008; g += 256) {
        int r = g >> 4, c = (g & 15) * 4;
        *(ushort4*)&rel[r * 64 + c] = *(const ushort4*)(relW + g * 4);
    }
    if (tid < 16) { ushort4 z = {0, 0, 0, 0}; *(ushort4*)&rel[63 * 64 + tid * 4] = z; }
    __syncthreads();
    {   // Tw = Q . relW^T
        f32x4 tacc[4] = {};
        #pragma unroll
        for (int nb = 0; nb < 4; nb++) {
            bf16x8 r0 = *(const bf16x8*)&rel[(nb * 16 + lm) * 64 + lq * 8];
            bf16x8 r1 = *(const bf16x8*)&rel[(nb * 16 + lm) * 64 + 32 + lq * 8];
            tacc[nb] = __builtin_amdgcn_mfma_f32_16x16x32_bf16(bq0, r0, tacc[nb], 0, 0, 0);
            tacc[nb] = __builtin_amdgcn_mfma_f32_16x16x32_bf16(bq1, r1, tacc[nb], 0, 0, 0);
        }
        #pragma unroll
        for (int nb = 0; nb < 4; nb++)
            #pragma unroll
            for (int rr = 0; rr < 4; rr++)
                Tw[(w * 16 + lq * 4 + rr) * LDT + nb * 16 + lm] = f2b(tacc[nb][rr]);
    }
    const int qw = (w & 1) * 16 + lm;
    float rwc[8];
    #pragma unroll
    for (int mb2 = 0; mb2 < 2; mb2++)
        #pragma unroll
        for (int rr = 0; rr < 4; rr++) {
            const int kw = mb2 * 16 + lq * 4 + rr;
            rwc[mb2 * 4 + rr] = b2f(Tw[(w * 16 + lm) * LDT + qw - kw + 31]) - 16.0f;
        }
    const int qh = (q0 >> 5) + (w >= 2 ? 1 : 0);

    const int srow = lane >> 3;
    const int sgcol = ((lane & 7) ^ (srow & 7)) * 8;       // swizzled global col
    const int sw0 = (lq ^ (lm & 7)) * 8;
    const int sw1 = ((lq + 4) ^ (lm & 7)) * 8;
    float l_acc = 0.f;
    f32x4 oacc[4] = {};

    __syncthreads();              // all rel readers done; vsT buf0 reusable
    // prime tile 0 into buf 0
    #pragma unroll
    for (int c4 = 0; c4 < 2; c4++) {
        const int c = w * 2 + c4;
        const int row = c * 8 + srow;
        __builtin_amdgcn_global_load_lds(
            (gu32*)(kgb + row * 64 + sgcol), (lu32*)&ks2[c * 512], 16, 0, 0);
        __builtin_amdgcn_global_load_lds(
            (gu32*)(vgb + row * 64 + sgcol), (lu32*)&vsT[c * 512], 16, 0, 0);
    }

    #pragma unroll 1
    for (int kt = 0; kt < 16; kt++) {
        __syncthreads();           // buf[kt&1] DMA complete; its prior readers done
        const int bo = (kt & 1) * 4096;
        if (kt < 15) {             // issue DMA for kt+1 into the other buffer
            const int bn1 = ((kt + 1) & 1) * 4096;
            const u16* kp = kgb + (size_t)(kt + 1) * 4096;
            const u16* vp = vgb + (size_t)(kt + 1) * 4096;
            #pragma unroll
            for (int c4 = 0; c4 < 2; c4++) {
                const int c = w * 2 + c4;
                const int row = c * 8 + srow;
                __builtin_amdgcn_global_load_lds(
                    (gu32*)(kp + row * 64 + sgcol), (lu32*)&ks2[bn1 + c * 512], 16, 0, 0);
                __builtin_amdgcn_global_load_lds(
                    (gu32*)(vp + row * 64 + sgcol), (lu32*)&vsT[bn1 + c * 512], 16, 0, 0);
            }
        }
        f32x4 sacc[4];
        #pragma unroll
        for (int mb = 0; mb < 4; mb++) {
            bf16x8 ka0 = *(const bf16x8*)&ks2[bo + (mb * 16 + lm) * 64 + sw0];
            bf16x8 ka1 = *(const bf16x8*)&ks2[bo + (mb * 16 + lm) * 64 + sw1];
            f32x4 s = {};
            s = __builtin_amdgcn_mfma_f32_16x16x32_bf16(ka0, bq0, s, 0, 0, 0);
            s = __builtin_amdgcn_mfma_f32_16x16x32_bf16(ka1, bq1, s, 0, 0, 0);
            sacc[mb] = s;
        }
        const float rh0 = b2f(Th[(w * 16 + lm) * LDT + qh - 2 * kt + 31]);
        const float rh1 = b2f(Th[(w * 16 + lm) * LDT + qh - 2 * kt + 30]);
        #pragma unroll
        for (int mb = 0; mb < 4; mb++) {
            const float rhv = (mb >= 2) ? rh1 : rh0;
            unsigned pk[2];
            #pragma unroll
            for (int h = 0; h < 2; h++) {
                float p0 = exp2f(sacc[mb][2 * h]     + rhv + rwc[(mb & 1) * 4 + 2 * h]);
                float p1 = exp2f(sacc[mb][2 * h + 1] + rhv + rwc[(mb & 1) * 4 + 2 * h + 1]);
                l_acc += p0; l_acc += p1;
                unsigned u0, u1;
                __builtin_memcpy(&u0, &p0, 4); __builtin_memcpy(&u1, &p1, 4);
                pk[h] = __builtin_amdgcn_perm(u1 + 0x8000u, u0 + 0x8000u, 0x07060302u);
            }
            uint2 u = {pk[0], pk[1]};
            *(uint2*)&pT[(w * 16 + lm) * LDT + mb * 16 + lq * 4] = u;   // wave-private
        }
        const bf16x8 pa0 = *(const bf16x8*)&pT[(w * 16 + lm) * LDT + lq * 8];
        const bf16x8 pa1 = *(const bf16x8*)&pT[(w * 16 + lm) * LDT + 32 + lq * 8];
        #pragma unroll
        for (int nb = 0; nb < 4; nb++) {
            bf16x8 vb0 = *(const bf16x8*)&vsT[bo + (nb * 16 + lm) * 64 + sw0];
            bf16x8 vb1 = *(const bf16x8*)&vsT[bo + (nb * 16 + lm) * 64 + sw1];
            oacc[nb] = __builtin_amdgcn_mfma_f32_16x16x32_bf16(pa0, vb0, oacc[nb], 0, 0, 0);
            oacc[nb] = __builtin_amdgcn_mfma_f32_16x16x32_bf16(pa1, vb1, oacc[nb], 0, 0, 0);
        }
    }
    l_acc += __shfl_xor(l_acc, 16);
    l_acc += __shfl_xor(l_acc, 32);
    const float rinv = 1.f / l_acc;
    float rv[4];
    #pragma unroll
    for (int rr = 0; rr < 4; rr++) rv[rr] = __shfl(rinv, lq * 4 + rr);
    const int bb = bn / 12, nh = bn % 12;
    #pragma unroll
    for (int nb = 0; nb < 4; nb++)
        #pragma unroll
        for (int rr = 0; rr < 4; rr++) {
            const int qrow = q0 + w * 16 + lq * 4 + rr;
            const int d = nb * 16 + lm;
            outb[((size_t)(bb * 1024 + qrow)) * 768 + nh * 64 + d] = f2b(oacc[nb][rr] * rv[rr]);
        }
}

// ---------------------------------------------------------------------------
extern "C" void kernel_launch(void* const* d_in, const int* in_sizes, int n_in,
                              void* d_out, int out_size, void* d_ws, size_t ws_size,
                              hipStream_t stream)
{
    u16* ws16  = (u16*)d_ws;
    u16* qkvT  = ws16;
    u16* xb    = ws16 + (size_t)18874368;
    u16* attn  = xb;                       // x dead after K1
    const size_t S = 25165824;
    u16* qkvw_b = ws16 + S;
    u16* projw_b = qkvw_b + 1769472;
    u16* qkvb_b = projw_b + 589824;
    u16* projb_b = qkvb_b + 2304;
    u16* relh_b = projb_b + 768;
    u16* relw_b = relh_b + 4032;
    int* flag = (int*)(ws16 + S + 2370432);

    detect_dtype<<<1, 64, 0, stream>>>((const u16*)d_in[0], flag);

    CvtArgs ca;
    ca.src[0] = d_in[0]; ca.dst[0] = xb;      ca.n[0] = 6291456; ca.sc[0] = 1.0f;
    ca.src[1] = d_in[1]; ca.dst[1] = qkvw_b;  ca.n[1] = 1769472; ca.sc[1] = 1.0f;
    ca.src[2] = d_in[3]; ca.dst[2] = projw_b; ca.n[2] = 589824;  ca.sc[2] = 1.0f;
    ca.src[3] = d_in[2]; ca.dst[3] = qkvb_b;  ca.n[3] = 2304;    ca.sc[3] = 1.0f;
    ca.src[4] = d_in[4]; ca.dst[4] = projb_b; ca.n[4] = 768;     ca.sc[4] = 1.0f;
    ca.src[5] = d_in[5]; ca.dst[5] = relh_b;  ca.n[5] = 4032;    ca.sc[5] = LOG2E;
    ca.src[6] = d_in[6]; ca.dst[6] = relw_b;  ca.n[6] = 4032;    ca.sc[6] = LOG2E;
    convert_all<<<2048, 256, 0, stream>>>(ca, flag);

    gemm128<1><<<dim3(64, 18), 256, 0, stream>>>(xb, qkvw_b, qkvb_b, nullptr, flag, qkvT, 2304, 768);
    flash_attn_mfma<<<dim3(96, 16), 256, 0, stream>>>(qkvT, relh_b, relw_b, attn);
    gemm128<0><<<dim3(64, 6), 256, 0, stream>>>(attn, projw_b, projb_b, d_out, flag, nullptr, 768, 768);
}

// Round 2
// 233.737 us; speedup vs baseline: 1.0635x; 1.0635x over previous
//
#include <hip/hip_runtime.h>

// R9: XOR-swizzled global_load_lds staging (gemm + flash), flash K/V dbuf with
// one barrier/round. R10: baseline resubmit (248.6us; flash 86.5us, Occ 20.4%,
// VALU 50%, Mfma 12.7% -> latency-bound at 2 blocks/CU from 60416B LDS).
// R11: flash occupancy 2->3 blocks/CU: LDS 60416->49408 by (a) Q/pT into one
// swizzled [64][64] 8KB buffer (Q staged via DMA, pT swizzled fixes its write
// conflicts), (b) Tw scratch folded into ks2 (pre-prime), (c) Th at stride 66.
// VALU cuts: v_cvt_pk_bf16_f32 replaces add+perm RTNE pack (-16 ops/round);
// P row-sums moved to MFMA pipe via ones-matrix (-16 adds/round, no end shfl).

typedef unsigned short u16;
typedef __attribute__((ext_vector_type(8))) __bf16 bf16x8;
typedef __attribute__((ext_vector_type(4))) float f32x4;
typedef __attribute__((address_space(1))) const unsigned int gu32;
typedef __attribute__((address_space(3))) unsigned int lu32;

#define LOG2E 1.4426950408889634f

__device__ __forceinline__ float b2f(u16 u) {
    unsigned int i = ((unsigned int)u) << 16;
    float f; __builtin_memcpy(&f, &i, 4); return f;
}
__device__ __forceinline__ u16 f2b(float f) {
    unsigned int x; __builtin_memcpy(&x, &f, 4);
    x += 0x7fffu + ((x >> 16) & 1u);   // RTNE
    return (u16)(x >> 16);
}

#define LDT 72

// ---------------------------------------------------------------------------
__global__ void detect_dtype(const u16* __restrict__ x, int* __restrict__ flag)
{
    if (threadIdx.x == 0 && blockIdx.x == 0) {
        float mx = 0.f;
        for (int i = 0; i < 128; i++) {
            float v = fabsf(b2f(x[i]));
            if (!(v <= 1e30f)) v = 1e30f;
            mx = fmaxf(mx, v);
        }
        *flag = (mx > 1e4f) ? 1 : 0;
    }
}

struct CvtArgs {
    const void* src[7];
    u16*        dst[7];
    int         n[7];
    float       sc[7];
};

__global__ __launch_bounds__(256) void convert_all(CvtArgs a, const int* __restrict__ flag)
{
    const int fl = *flag;
    const int g = blockIdx.x * 256 + threadIdx.x;
    const int stride = gridDim.x * 256;
    #pragma unroll 1
    for (int s = 0; s < 7; s++) {
        const int n = a.n[s];
        const float sc = a.sc[s];
        const float* fs = (const float*)a.src[s];
        const u16*  hs = (const u16*)a.src[s];
        u16* d = a.dst[s];
        for (int i = g; i < n; i += stride) {
            float v = fl ? fs[i] : b2f(hs[i]);
            d[i] = f2b(v * sc);
        }
    }
}

// ---------------------------------------------------------------------------
// 128x128 GEMM (TN), BK=64, swizzled global_load_lds staging.
// EPI=0: proj (dual-dtype store). EPI=1: qkv (rope/scale; LDS-staged stores;
// V -> [bn][kt][d][l64] tile-contiguous).
// ---------------------------------------------------------------------------
template <int EPI>
__global__ __launch_bounds__(256) void gemm128(
    const u16* __restrict__ A, const u16* __restrict__ Bw,
    const u16* __restrict__ bias, void* __restrict__ Cout,
    const int* __restrict__ flag, u16* __restrict__ qkvT, int N, int K)
{
    __shared__ __align__(16) u16 smem[16384];    // lA|lB; reused as ct[128][128]
    u16* lA = smem;
    u16* lB = smem + 8192;
    u16* ct = smem;
    const int tid = threadIdx.x;
    const int m0 = blockIdx.x * 128, n0 = blockIdx.y * 128;
    const int wave = tid >> 6, lane = tid & 63;
    const int wm = (wave & 1) * 64, wn = (wave >> 1) * 64;
    const int lm = lane & 15, lq = lane >> 4;
    const int srow = lane >> 3;
    const int sgcol = ((lane & 7) ^ (srow & 7)) * 8;       // swizzled global col
    const int sw0 = (lq ^ (lm & 7)) * 8;                   // frag col, group lq
    const int sw1 = ((lq + 4) ^ (lm & 7)) * 8;             // frag col, group lq+4
    f32x4 acc[4][4] = {};
    for (int k0 = 0; k0 < K; k0 += 64) {
        if (k0) __syncthreads();
        #pragma unroll
        for (int c4 = 0; c4 < 4; c4++) {
            const int c = wave * 4 + c4;
            const int row = c * 8 + srow;
            __builtin_amdgcn_global_load_lds(
                (gu32*)(A + (size_t)(m0 + row) * K + k0 + sgcol),
                (lu32*)&lA[c * 512], 16, 0, 0);
            __builtin_amdgcn_global_load_lds(
                (gu32*)(Bw + (size_t)(n0 + row) * K + k0 + sgcol),
                (lu32*)&lB[c * 512], 16, 0, 0);
        }
        __syncthreads();
        #pragma unroll
        for (int ks = 0; ks < 64; ks += 32) {
            const int sw = ks ? sw1 : sw0;
            bf16x8 af[4], bfr[4];
            #pragma unroll
            for (int i = 0; i < 4; i++) af[i]  = *(const bf16x8*)&lA[(wm + i * 16 + lm) * 64 + sw];
            #pragma unroll
            for (int j = 0; j < 4; j++) bfr[j] = *(const bf16x8*)&lB[(wn + j * 16 + lm) * 64 + sw];
            #pragma unroll
            for (int i = 0; i < 4; i++)
                #pragma unroll
                for (int j = 0; j < 4; j++)
                    acc[i][j] = __builtin_amdgcn_mfma_f32_16x16x32_bf16(af[i], bfr[j], acc[i][j], 0, 0, 0);
        }
    }
    if (EPI == 0) {
        const int fl = *flag;
        #pragma unroll
        for (int j = 0; j < 4; j++) {
            const int n = n0 + wn + j * 16 + lm;
            const float bj = b2f(bias[n]);
            #pragma unroll
            for (int i = 0; i < 4; i++)
                #pragma unroll
                for (int r = 0; r < 4; r++) {
                    const int m = m0 + wm + i * 16 + lq * 4 + r;
                    const float v = acc[i][j][r] + bj;
                    if (fl) ((float*)Cout)[(size_t)m * 768 + n] = v;
                    else    ((u16*)Cout)[(size_t)m * 768 + n] = f2b(v);
                }
        }
    } else {
        const int which = n0 / 768;
        const bool vt = (which == 2);
        __syncthreads();
        #pragma unroll
        for (int j = 0; j < 4; j++) {
            const int nl = wn + j * 16 + lm;
            const int n = n0 + nl;
            const float bj = b2f(bias[n]);
            #pragma unroll
            for (int i = 0; i < 4; i++)
                #pragma unroll
                for (int r = 0; r < 4; r++) {
                    const int ml = wm + i * 16 + lq * 4 + r;
                    const int m = m0 + ml;
                    float v = acc[i][j][r] + bj;
                    const float p = __shfl_xor(v, 1);
                    const int l = m & 1023, d = n & 63;
                    float o = v;
                    if (which < 2) {
                        const int pi = d >> 1, jj = pi & 15;
                        const float coord = (pi < 16) ? (float)(l & 31) : (float)(l >> 5);
                        const float ang = coord * __expf(-(float)jj * 0.5756462732485115f);
                        float sn, cs; __sincosf(ang, &sn, &cs);
                        o = v * cs + ((d & 1) ? p * sn : -(p * sn));
                        if (which == 1) o *= 0.125f * LOG2E;
                    }
                    ct[vt ? nl * 128 + ml : ml * 128 + nl] = f2b(o);
                }
        }
        __syncthreads();
        const size_t HL = (size_t)96 * 1024 * 64;
        const int nh0 = (n0 >> 6) % 12, bb = m0 >> 10, l0 = m0 & 1023;
        if (!vt) {
            #pragma unroll
            for (int pass = 0; pass < 8; pass++) {
                const int chunk = pass * 256 + tid;
                const int run = chunk >> 3, lc = chunk & 7;
                const int ml = run >> 1, h = run & 1;
                u16* gp = qkvT + (size_t)which * HL
                        + ((size_t)(bb * 12 + nh0 + h) * 1024 + l0 + ml) * 64 + lc * 8;
                *(uint4*)gp = *(const uint4*)&ct[ml * 128 + h * 64 + lc * 8];
            }
        } else {
            const int kt0 = l0 >> 6;
            #pragma unroll
            for (int pass = 0; pass < 8; pass++) {
                const int run = pass * 16 + (tid >> 4);
                const int ln = tid & 15;
                const int half = ln >> 3, l8 = ln & 7;
                u16* gp = qkvT + 2 * HL
                        + (size_t)(bb * 12 + nh0 + (run >> 6)) * 65536
                        + (size_t)(kt0 + half) * 4096 + (run & 63) * 64 + l8 * 8;
                *(uint4*)gp = *(const uint4*)&ct[run * 128 + ln * 8];
            }
        }
    }
}

// ---------------------------------------------------------------------------
// K2: MFMA flash attention. 49408B LDS -> 3 blocks/CU. Q/pT share one
// swizzled [64][64] buffer; Tw scratch in ks2; Th persistent at stride 66.
// cvt_pk_bf16 pack; P row-sums on MFMA pipe (ones matrix).
// ---------------------------------------------------------------------------
__global__ __launch_bounds__(256) void flash_attn_mfma(
    const u16* __restrict__ qkvT, const u16* __restrict__ relH,
    const u16* __restrict__ relW, u16* __restrict__ outb)
{
    __shared__ __align__(16) u16 ks2[2 * 4096];    // K dbuf (swz); prologue: Tw scratch [64][66]
    __shared__ __align__(16) u16 vsT[2 * 4096];    // V dbuf (swz); prologue: rel staging (buf0)
    __shared__ __align__(16) u16 pq[4096];         // Q staging (swz) -> pT (swz)
    __shared__ __align__(16) u16 ThL[64 * 66];     // Th, persistent through main loop
    u16* rel = vsT;

    const int tid = threadIdx.x;
    const int w = tid >> 6, lane = tid & 63;
    const int lm = lane & 15, lq = lane >> 4;
    const int srow = lane >> 3;
    const int sgcol = ((lane & 7) ^ (srow & 7)) * 8;   // swizzled global col
    const int sw0 = (lq ^ (lm & 7)) * 8;
    const int sw1 = ((lq + 4) ^ (lm & 7)) * 8;

    const int bn = blockIdx.x, q0 = blockIdx.y * 64;
    const size_t HL = (size_t)96 * 1024 * 64;
    const u16* qg  = qkvT + (size_t)bn * 65536 + (size_t)q0 * 64;
    const u16* kgb = qkvT + HL + (size_t)bn * 65536;
    const u16* vgb = qkvT + 2 * HL + (size_t)bn * 65536;   // [kt][d][l64]

    // Q -> pq via swizzled DMA (same pattern as K/V staging)
    #pragma unroll
    for (int c4 = 0; c4 < 2; c4++) {
        const int c = w * 2 + c4;
        const int row = c * 8 + srow;
        __builtin_amdgcn_global_load_lds(
            (gu32*)(qg + row * 64 + sgcol), (lu32*)&pq[c * 512], 16, 0, 0);
    }
    // relH -> vsT buf0 (unswizzled [64][64])
    for (int g = tid; g < 1008; g += 256) {
        int r = g >> 4, c = (g & 15) * 4;
        *(ushort4*)&rel[r * 64 + c] = *(const ushort4*)(relH + g * 4);
    }
    if (tid < 16) { ushort4 z = {0, 0, 0, 0}; *(ushort4*)&rel[63 * 64 + tid * 4] = z; }
    __syncthreads();                                   // B1: Q DMA + relH staged

    const bf16x8 bq0 = *(const bf16x8*)&pq[(w * 16 + lm) * 64 + sw0];
    const bf16x8 bq1 = *(const bf16x8*)&pq[(w * 16 + lm) * 64 + sw1];

    {   // Th = Q . relH^T  -> ThL [64][66]
        f32x4 tacc[4] = {};
        #pragma unroll
        for (int nb = 0; nb < 4; nb++) {
            bf16x8 r0 = *(const bf16x8*)&rel[(nb * 16 + lm) * 64 + lq * 8];
            bf16x8 r1 = *(const bf16x8*)&rel[(nb * 16 + lm) * 64 + 32 + lq * 8];
            tacc[nb] = __builtin_amdgcn_mfma_f32_16x16x32_bf16(bq0, r0, tacc[nb], 0, 0, 0);
            tacc[nb] = __builtin_amdgcn_mfma_f32_16x16x32_bf16(bq1, r1, tacc[nb], 0, 0, 0);
        }
        #pragma unroll
        for (int nb = 0; nb < 4; nb++)
            #pragma unroll
            for (int rr = 0; rr < 4; rr++)
                ThL[(w * 16 + lq * 4 + rr) * 66 + nb * 16 + lm] = f2b(tacc[nb][rr]);
    }
    __syncthreads();                                   // B2: relH reads done
    for (int g = tid; g < 1008; g += 256) {
        int r = g >> 4, c = (g & 15) * 4;
        *(ushort4*)&rel[r * 64 + c] = *(const ushort4*)(relW + g * 4);
    }
    if (tid < 16) { ushort4 z = {0, 0, 0, 0}; *(ushort4*)&rel[63 * 64 + tid * 4] = z; }
    __syncthreads();                                   // B3: relW staged
    {   // Tw = Q . relW^T -> ks2 scratch [64][66]
        f32x4 tacc[4] = {};
        #pragma unroll
        for (int nb = 0; nb < 4; nb++) {
            bf16x8 r0 = *(const bf16x8*)&rel[(nb * 16 + lm) * 64 + lq * 8];
            bf16x8 r1 = *(const bf16x8*)&rel[(nb * 16 + lm) * 64 + 32 + lq * 8];
            tacc[nb] = __builtin_amdgcn_mfma_f32_16x16x32_bf16(bq0, r0, tacc[nb], 0, 0, 0);
            tacc[nb] = __builtin_amdgcn_mfma_f32_16x16x32_bf16(bq1, r1, tacc[nb], 0, 0, 0);
        }
        #pragma unroll
        for (int nb = 0; nb < 4; nb++)
            #pragma unroll
            for (int rr = 0; rr < 4; rr++)
                ks2[(w * 16 + lq * 4 + rr) * 66 + nb * 16 + lm] = f2b(tacc[nb][rr]);
    }
    __syncthreads();                                   // B4: Tw written
    const int qw = (w & 1) * 16 + lm;
    float rwc[8];
    #pragma unroll
    for (int mb2 = 0; mb2 < 2; mb2++)
        #pragma unroll
        for (int rr = 0; rr < 4; rr++) {
            const int kw = mb2 * 16 + lq * 4 + rr;
            rwc[mb2 * 4 + rr] = b2f(ks2[(w * 16 + lm) * 66 + qw - kw + 31]) - 16.0f;
        }
    const int qh = (q0 >> 5) + (w >= 2 ? 1 : 0);

    // ones B-fragment for P row-sums on the MFMA pipe
    union { unsigned u[4]; bf16x8 v; } uo;
    uo.u[0] = uo.u[1] = uo.u[2] = uo.u[3] = 0x3F803F80u;
    const bf16x8 vone = uo.v;

    f32x4 lacc = {};
    f32x4 oacc[4] = {};

    __syncthreads();                                   // B5: scratch readers done
    // prime tile 0 into buf 0
    #pragma unroll
    for (int c4 = 0; c4 < 2; c4++) {
        const int c = w * 2 + c4;
        const int row = c * 8 + srow;
        __builtin_amdgcn_global_load_lds(
            (gu32*)(kgb + row * 64 + sgcol), (lu32*)&ks2[c * 512], 16, 0, 0);
        __builtin_amdgcn_global_load_lds(
            (gu32*)(vgb + row * 64 + sgcol), (lu32*)&vsT[c * 512], 16, 0, 0);
    }

    #pragma unroll 1
    for (int kt = 0; kt < 16; kt++) {
        __syncthreads();           // buf[kt&1] DMA complete; its prior readers done
        const int bo = (kt & 1) * 4096;
        if (kt < 15) {             // issue DMA for kt+1 into the other buffer
            const int bn1 = ((kt + 1) & 1) * 4096;
            const u16* kp = kgb + (size_t)(kt + 1) * 4096;
            const u16* vp = vgb + (size_t)(kt + 1) * 4096;
            #pragma unroll
            for (int c4 = 0; c4 < 2; c4++) {
                const int c = w * 2 + c4;
                const int row = c * 8 + srow;
                __builtin_amdgcn_global_load_lds(
                    (gu32*)(kp + row * 64 + sgcol), (lu32*)&ks2[bn1 + c * 512], 16, 0, 0);
                __builtin_amdgcn_global_load_lds(
                    (gu32*)(vp + row * 64 + sgcol), (lu32*)&vsT[bn1 + c * 512], 16, 0, 0);
            }
        }
        f32x4 sacc[4];
        #pragma unroll
        for (int mb = 0; mb < 4; mb++) {
            bf16x8 ka0 = *(const bf16x8*)&ks2[bo + (mb * 16 + lm) * 64 + sw0];
            bf16x8 ka1 = *(const bf16x8*)&ks2[bo + (mb * 16 + lm) * 64 + sw1];
            f32x4 s = {};
            s = __builtin_amdgcn_mfma_f32_16x16x32_bf16(ka0, bq0, s, 0, 0, 0);
            s = __builtin_amdgcn_mfma_f32_16x16x32_bf16(ka1, bq1, s, 0, 0, 0);
            sacc[mb] = s;
        }
        const float rh0 = b2f(ThL[(w * 16 + lm) * 66 + qh - 2 * kt + 31]);
        const float rh1 = b2f(ThL[(w * 16 + lm) * 66 + qh - 2 * kt + 30]);
        #pragma unroll
        for (int mb = 0; mb < 4; mb++) {
            const float rhv = (mb >= 2) ? rh1 : rh0;
            float p0 = exp2f(sacc[mb][0] + rhv + rwc[(mb & 1) * 4 + 0]);
            float p1 = exp2f(sacc[mb][1] + rhv + rwc[(mb & 1) * 4 + 1]);
            float p2 = exp2f(sacc[mb][2] + rhv + rwc[(mb & 1) * 4 + 2]);
            float p3 = exp2f(sacc[mb][3] + rhv + rwc[(mb & 1) * 4 + 3]);
            unsigned w0, w1;
            asm("v_cvt_pk_bf16_f32 %0, %1, %2" : "=v"(w0) : "v"(p0), "v"(p1));
            asm("v_cvt_pk_bf16_f32 %0, %1, %2" : "=v"(w1) : "v"(p2), "v"(p3));
            uint2 u; u.x = w0; u.y = w1;
            const int gg = 2 * mb + (lq >> 1);         // 16B group of col mb*16+lq*4
            *(uint2*)&pq[(w * 16 + lm) * 64 + ((gg ^ (lm & 7)) * 8) + (lq & 1) * 4] = u;
        }
        const bf16x8 pa0 = *(const bf16x8*)&pq[(w * 16 + lm) * 64 + sw0];
        const bf16x8 pa1 = *(const bf16x8*)&pq[(w * 16 + lm) * 64 + sw1];
        lacc = __builtin_amdgcn_mfma_f32_16x16x32_bf16(pa0, vone, lacc, 0, 0, 0);
        lacc = __builtin_amdgcn_mfma_f32_16x16x32_bf16(pa1, vone, lacc, 0, 0, 0);
        #pragma unroll
        for (int nb = 0; nb < 4; nb++) {
            bf16x8 vb0 = *(const bf16x8*)&vsT[bo + (nb * 16 + lm) * 64 + sw0];
            bf16x8 vb1 = *(const bf16x8*)&vsT[bo + (nb * 16 + lm) * 64 + sw1];
            oacc[nb] = __builtin_amdgcn_mfma_f32_16x16x32_bf16(pa0, vb0, oacc[nb], 0, 0, 0);
            oacc[nb] = __builtin_amdgcn_mfma_f32_16x16x32_bf16(pa1, vb1, oacc[nb], 0, 0, 0);
        }
    }
    // lacc[rr] = sum_k P[q = w*16+lq*4+rr][k]  (replicated across cols)
    float rv[4];
    #pragma unroll
    for (int rr = 0; rr < 4; rr++) rv[rr] = 1.f / lacc[rr];
    const int bb = bn / 12, nh = bn % 12;
    #pragma unroll
    for (int nb = 0; nb < 4; nb++)
        #pragma unroll
        for (int rr = 0; rr < 4; rr++) {
            const int qrow = q0 + w * 16 + lq * 4 + rr;
            const int d = nb * 16 + lm;
            outb[((size_t)(bb * 1024 + qrow)) * 768 + nh * 64 + d] = f2b(oacc[nb][rr] * rv[rr]);
        }
}

// ---------------------------------------------------------------------------
extern "C" void kernel_launch(void* const* d_in, const int* in_sizes, int n_in,
                              void* d_out, int out_size, void* d_ws, size_t ws_size,
                              hipStream_t stream)
{
    u16* ws16  = (u16*)d_ws;
    u16* qkvT  = ws16;
    u16* xb    = ws16 + (size_t)18874368;
    u16* attn  = xb;                       // x dead after K1
    const size_t S = 25165824;
    u16* qkvw_b = ws16 + S;
    u16* projw_b = qkvw_b + 1769472;
    u16* qkvb_b = projw_b + 589824;
    u16* projb_b = qkvb_b + 2304;
    u16* relh_b = projb_b + 768;
    u16* relw_b = relh_b + 4032;
    int* flag = (int*)(ws16 + S + 2370432);

    detect_dtype<<<1, 64, 0, stream>>>((const u16*)d_in[0], flag);

    CvtArgs ca;
    ca.src[0] = d_in[0]; ca.dst[0] = xb;      ca.n[0] = 6291456; ca.sc[0] = 1.0f;
    ca.src[1] = d_in[1]; ca.dst[1] = qkvw_b;  ca.n[1] = 1769472; ca.sc[1] = 1.0f;
    ca.src[2] = d_in[3]; ca.dst[2] = projw_b; ca.n[2] = 589824;  ca.sc[2] = 1.0f;
    ca.src[3] = d_in[2]; ca.dst[3] = qkvb_b;  ca.n[3] = 2304;    ca.sc[3] = 1.0f;
    ca.src[4] = d_in[4]; ca.dst[4] = projb_b; ca.n[4] = 768;     ca.sc[4] = 1.0f;
    ca.src[5] = d_in[5]; ca.dst[5] = relh_b;  ca.n[5] = 4032;    ca.sc[5] = LOG2E;
    ca.src[6] = d_in[6]; ca.dst[6] = relw_b;  ca.n[6] = 4032;    ca.sc[6] = LOG2E;
    convert_all<<<2048, 256, 0, stream>>>(ca, flag);

    gemm128<1><<<dim3(64, 18), 256, 0, stream>>>(xb, qkvw_b, qkvb_b, nullptr, flag, qkvT, 2304, 768);
    flash_attn_mfma<<<dim3(96, 16), 256, 0, stream>>>(qkvT, relh_b, relw_b, attn);
    gemm128<0><<<dim3(64, 6), 256, 0, stream>>>(attn, projw_b, projb_b, d_out, flag, nullptr, 768, 768);
}

// Round 7
// 225.061 us; speedup vs baseline: 1.1045x; 1.0385x over previous
//
#include <hip/hip_runtime.h>

// R10: baseline 248.6us (flash 86.5, Occ 20.4%, 2 blk/CU).
// R11: flash LDS 60416->49664 -> 3 blk/CU; cvt_pk pack; lsum on MFMA pipe.
//      233.7us (flash 72.4, Occ 27.7, Mfma 17.4, VALU 55.7).
// R12: flash QBLK=128 (grid 96x8 = 768 blocks = exactly 3/CU, no tail):
//      round overheads amortized over 2x MFMA work; two independent Q-half
//      streams for ILP; K frags read once/round shared by both halves; bias
//      folded into sacc init; Q direct global->reg; ThL window [128][36].
//      LDS 50176B -> still 3 blk/CU. (Never executed: R12-R14 broker timeouts.)
// R15: flash unchanged. NEW: qkv rope epilogue trig table (512 distinct
//      angles; same __expf/__sincosf -> bit-identical, absmax unchanged);
//      replaces 64 sincosf + 4 expf per thread with <=2-way-bank ds_reads.
// R16: identical resubmit — R13-R15 all failed with GPUAcquisitionTimeout
//      (broker capacity; kernel never reached the device).

typedef unsigned short u16;
typedef __attribute__((ext_vector_type(8))) __bf16 bf16x8;
typedef __attribute__((ext_vector_type(4))) float f32x4;
typedef __attribute__((address_space(1))) const unsigned int gu32;
typedef __attribute__((address_space(3))) unsigned int lu32;

#define LOG2E 1.4426950408889634f

__device__ __forceinline__ float b2f(u16 u) {
    unsigned int i = ((unsigned int)u) << 16;
    float f; __builtin_memcpy(&f, &i, 4); return f;
}
__device__ __forceinline__ u16 f2b(float f) {
    unsigned int x; __builtin_memcpy(&x, &f, 4);
    x += 0x7fffu + ((x >> 16) & 1u);   // RTNE
    return (u16)(x >> 16);
}

// ---------------------------------------------------------------------------
__global__ void detect_dtype(const u16* __restrict__ x, int* __restrict__ flag)
{
    if (threadIdx.x == 0 && blockIdx.x == 0) {
        float mx = 0.f;
        for (int i = 0; i < 128; i++) {
            float v = fabsf(b2f(x[i]));
            if (!(v <= 1e30f)) v = 1e30f;
            mx = fmaxf(mx, v);
        }
        *flag = (mx > 1e4f) ? 1 : 0;
    }
}

struct CvtArgs {
    const void* src[7];
    u16*        dst[7];
    int         n[7];
    float       sc[7];
};

__global__ __launch_bounds__(256) void convert_all(CvtArgs a, const int* __restrict__ flag)
{
    const int fl = *flag;
    const int g = blockIdx.x * 256 + threadIdx.x;
    const int stride = gridDim.x * 256;
    #pragma unroll 1
    for (int s = 0; s < 7; s++) {
        const int n = a.n[s];
        const float sc = a.sc[s];
        const float* fs = (const float*)a.src[s];
        const u16*  hs = (const u16*)a.src[s];
        u16* d = a.dst[s];
        for (int i = g; i < n; i += stride) {
            float v = fl ? fs[i] : b2f(hs[i]);
            d[i] = f2b(v * sc);
        }
    }
}

// ---------------------------------------------------------------------------
// 128x128 GEMM (TN), BK=64, swizzled global_load_lds staging.
// EPI=0: proj (dual-dtype store). EPI=1: qkv (rope via LDS trig table;
// LDS-staged stores; V -> [bn][kt][d][l64] tile-contiguous).
// ---------------------------------------------------------------------------
template <int EPI>
__global__ __launch_bounds__(256) void gemm128(
    const u16* __restrict__ A, const u16* __restrict__ Bw,
    const u16* __restrict__ bias, void* __restrict__ Cout,
    const int* __restrict__ flag, u16* __restrict__ qkvT, int N, int K)
{
    __shared__ __align__(16) u16 smem[16384];    // lA|lB; reused as ct[128][128]
    __shared__ float tabc[512];                  // rope cos table [coord][jj] (EPI==1)
    __shared__ float tabs[512];                  // rope sin table
    u16* lA = smem;
    u16* lB = smem + 8192;
    u16* ct = smem;
    const int tid = threadIdx.x;
    const int m0 = blockIdx.x * 128, n0 = blockIdx.y * 128;
    const int wave = tid >> 6, lane = tid & 63;
    const int wm = (wave & 1) * 64, wn = (wave >> 1) * 64;
    const int lm = lane & 15, lq = lane >> 4;
    const int srow = lane >> 3;
    const int sgcol = ((lane & 7) ^ (srow & 7)) * 8;       // swizzled global col
    const int sw0 = (lq ^ (lm & 7)) * 8;                   // frag col, group lq
    const int sw1 = ((lq + 4) ^ (lm & 7)) * 8;             // frag col, group lq+4

    if (EPI == 1) {
        // 512 entries, 2/thread; same __expf/__sincosf as the old per-element
        // path -> bit-identical values. Visible after the k0-loop's barriers.
        #pragma unroll
        for (int e = tid; e < 512; e += 256) {
            const int coord = e >> 4, jj = e & 15;
            const float ang = (float)coord * __expf(-(float)jj * 0.5756462732485115f);
            float sn, cs; __sincosf(ang, &sn, &cs);
            tabc[e] = cs; tabs[e] = sn;
        }
    }

    f32x4 acc[4][4] = {};
    for (int k0 = 0; k0 < K; k0 += 64) {
        if (k0) __syncthreads();
        #pragma unroll
        for (int c4 = 0; c4 < 4; c4++) {
            const int c = wave * 4 + c4;
            const int row = c * 8 + srow;
            __builtin_amdgcn_global_load_lds(
                (gu32*)(A + (size_t)(m0 + row) * K + k0 + sgcol),
                (lu32*)&lA[c * 512], 16, 0, 0);
            __builtin_amdgcn_global_load_lds(
                (gu32*)(Bw + (size_t)(n0 + row) * K + k0 + sgcol),
                (lu32*)&lB[c * 512], 16, 0, 0);
        }
        __syncthreads();
        #pragma unroll
        for (int ks = 0; ks < 64; ks += 32) {
            const int sw = ks ? sw1 : sw0;
            bf16x8 af[4], bfr[4];
            #pragma unroll
            for (int i = 0; i < 4; i++) af[i]  = *(const bf16x8*)&lA[(wm + i * 16 + lm) * 64 + sw];
            #pragma unroll
            for (int j = 0; j < 4; j++) bfr[j] = *(const bf16x8*)&lB[(wn + j * 16 + lm) * 64 + sw];
            #pragma unroll
            for (int i = 0; i < 4; i++)
                #pragma unroll
                for (int j = 0; j < 4; j++)
                    acc[i][j] = __builtin_amdgcn_mfma_f32_16x16x32_bf16(af[i], bfr[j], acc[i][j], 0, 0, 0);
        }
    }
    if (EPI == 0) {
        const int fl = *flag;
        #pragma unroll
        for (int j = 0; j < 4; j++) {
            const int n = n0 + wn + j * 16 + lm;
            const float bj = b2f(bias[n]);
            #pragma unroll
            for (int i = 0; i < 4; i++)
                #pragma unroll
                for (int r = 0; r < 4; r++) {
                    const int m = m0 + wm + i * 16 + lq * 4 + r;
                    const float v = acc[i][j][r] + bj;
                    if (fl) ((float*)Cout)[(size_t)m * 768 + n] = v;
                    else    ((u16*)Cout)[(size_t)m * 768 + n] = f2b(v);
                }
        }
    } else {
        const int which = n0 / 768;
        const bool vt = (which == 2);
        __syncthreads();
        #pragma unroll
        for (int j = 0; j < 4; j++) {
            const int nl = wn + j * 16 + lm;
            const int n = n0 + nl;
            const float bj = b2f(bias[n]);
            const int d = n & 63;
            const int pi = d >> 1;
            const int jj = pi & 15;
            #pragma unroll
            for (int i = 0; i < 4; i++)
                #pragma unroll
                for (int r = 0; r < 4; r++) {
                    const int ml = wm + i * 16 + lq * 4 + r;
                    const int m = m0 + ml;
                    float v = acc[i][j][r] + bj;
                    const float p = __shfl_xor(v, 1);
                    const int l = m & 1023;
                    float o = v;
                    if (which < 2) {
                        const int coord = (pi < 16) ? (l & 31) : (l >> 5);
                        const float cs = tabc[coord * 16 + jj];
                        const float sn = tabs[coord * 16 + jj];
                        o = v * cs + ((d & 1) ? p * sn : -(p * sn));
                        if (which == 1) o *= 0.125f * LOG2E;
                    }
                    ct[vt ? nl * 128 + ml : ml * 128 + nl] = f2b(o);
                }
        }
        __syncthreads();
        const size_t HL = (size_t)96 * 1024 * 64;
        const int nh0 = (n0 >> 6) % 12, bb = m0 >> 10, l0 = m0 & 1023;
        if (!vt) {
            #pragma unroll
            for (int pass = 0; pass < 8; pass++) {
                const int chunk = pass * 256 + tid;
                const int run = chunk >> 3, lc = chunk & 7;
                const int ml = run >> 1, h = run & 1;
                u16* gp = qkvT + (size_t)which * HL
                        + ((size_t)(bb * 12 + nh0 + h) * 1024 + l0 + ml) * 64 + lc * 8;
                *(uint4*)gp = *(const uint4*)&ct[ml * 128 + h * 64 + lc * 8];
            }
        } else {
            const int kt0 = l0 >> 6;
            #pragma unroll
            for (int pass = 0; pass < 8; pass++) {
                const int run = pass * 16 + (tid >> 4);
                const int ln = tid & 15;
                const int half = ln >> 3, l8 = ln & 7;
                u16* gp = qkvT + 2 * HL
                        + (size_t)(bb * 12 + nh0 + (run >> 6)) * 65536
                        + (size_t)(kt0 + half) * 4096 + (run & 63) * 64 + l8 * 8;
                *(uint4*)gp = *(const uint4*)&ct[run * 128 + ln * 8];
            }
        }
    }
}

// ---------------------------------------------------------------------------
// K2: MFMA flash attention, QBLK=128 (2 Q-halves per block), KVBLK=64.
// 50176B LDS -> 3 blocks/CU; 768 blocks = exactly 3/CU (no tail).
// K frags read once/round, reused by both halves; bias in sacc init.
// ---------------------------------------------------------------------------
__global__ __launch_bounds__(256, 3) void flash_attn_mfma(
    const u16* __restrict__ qkvT, const u16* __restrict__ relH,
    const u16* __restrict__ relW, u16* __restrict__ outb)
{
    __shared__ __align__(16) u16 ks2[2 * 4096];    // K dbuf (swz); prologue: Tw scratch [128][64]
    __shared__ __align__(16) u16 vsT[2 * 4096];    // V dbuf (swz); prologue: rel staging (buf0)
    __shared__ __align__(16) u16 ps[4096];         // P tile (swz), halves sequential
    __shared__ __align__(16) u16 ThL[128 * 36];    // Th col-window [qh0, qh0+34]
    u16* rel = vsT;
    u16* TwS = ks2;                                // [128][64] scratch, freed before DMA

    const int tid = threadIdx.x;
    const int w = tid >> 6, lane = tid & 63;
    const int lm = lane & 15, lq = lane >> 4;
    const int whi = (w >= 2) ? 1 : 0;
    const int srow = lane >> 3;
    const int sgcol = ((lane & 7) ^ (srow & 7)) * 8;   // swizzled global col
    const int sw0 = (lq ^ (lm & 7)) * 8;
    const int sw1 = ((lq + 4) ^ (lm & 7)) * 8;

    const int bn = blockIdx.x, q0 = blockIdx.y * 128;
    const int qh0 = blockIdx.y * 4;                // q0 >> 5
    const size_t HL = (size_t)96 * 1024 * 64;
    const u16* qg  = qkvT + (size_t)bn * 65536 + (size_t)q0 * 64;
    const u16* kgb = qkvT + HL + (size_t)bn * 65536;
    const u16* vgb = qkvT + 2 * HL + (size_t)bn * 65536;   // [kt][d][l64]

    // Q fragments: direct global -> registers (once per block)
    bf16x8 bq0[2], bq1[2];
    #pragma unroll
    for (int h = 0; h < 2; h++) {
        const u16* qr = qg + (h * 64 + w * 16 + lm) * 64;
        bq0[h] = *(const bf16x8*)(qr + lq * 8);
        bq1[h] = *(const bf16x8*)(qr + 32 + lq * 8);
    }

    // relH -> rel (vsT buf0, unswizzled [64][64])
    for (int g = tid; g < 1008; g += 256) {
        int r = g >> 4, c = (g & 15) * 4;
        *(ushort4*)&rel[r * 64 + c] = *(const ushort4*)(relH + g * 4);
    }
    if (tid < 16) { ushort4 z = {0, 0, 0, 0}; *(ushort4*)&rel[63 * 64 + tid * 4] = z; }
    __syncthreads();                                   // B1

    {   // Th = Q . relH^T -> ThL window [128][36]
        #pragma unroll
        for (int h = 0; h < 2; h++) {
            f32x4 tacc[4] = {};
            #pragma unroll
            for (int nb = 0; nb < 4; nb++) {
                bf16x8 r0 = *(const bf16x8*)&rel[(nb * 16 + lm) * 64 + lq * 8];
                bf16x8 r1 = *(const bf16x8*)&rel[(nb * 16 + lm) * 64 + 32 + lq * 8];
                tacc[nb] = __builtin_amdgcn_mfma_f32_16x16x32_bf16(bq0[h], r0, tacc[nb], 0, 0, 0);
                tacc[nb] = __builtin_amdgcn_mfma_f32_16x16x32_bf16(bq1[h], r1, tacc[nb], 0, 0, 0);
            }
            #pragma unroll
            for (int nb = 0; nb < 4; nb++)
                #pragma unroll
                for (int rr = 0; rr < 4; rr++) {
                    const unsigned cw = (unsigned)(nb * 16 + lm - qh0);
                    if (cw < 36u)
                        ThL[(h * 64 + w * 16 + lq * 4 + rr) * 36 + cw] = f2b(tacc[nb][rr]);
                }
        }
    }
    __syncthreads();                                   // B2: relH reads done
    for (int g = tid; g < 1008; g += 256) {
        int r = g >> 4, c = (g & 15) * 4;
        *(ushort4*)&rel[r * 64 + c] = *(const ushort4*)(relW + g * 4);
    }
    if (tid < 16) { ushort4 z = {0, 0, 0, 0}; *(ushort4*)&rel[63 * 64 + tid * 4] = z; }
    __syncthreads();                                   // B3: relW staged
    {   // Tw = Q . relW^T -> TwS [128][64]
        #pragma unroll
        for (int h = 0; h < 2; h++) {
            f32x4 tacc[4] = {};
            #pragma unroll
            for (int nb = 0; nb < 4; nb++) {
                bf16x8 r0 = *(const bf16x8*)&rel[(nb * 16 + lm) * 64 + lq * 8];
                bf16x8 r1 = *(const bf16x8*)&rel[(nb * 16 + lm) * 64 + 32 + lq * 8];
                tacc[nb] = __builtin_amdgcn_mfma_f32_16x16x32_bf16(bq0[h], r0, tacc[nb], 0, 0, 0);
                tacc[nb] = __builtin_amdgcn_mfma_f32_16x16x32_bf16(bq1[h], r1, tacc[nb], 0, 0, 0);
            }
            #pragma unroll
            for (int nb = 0; nb < 4; nb++)
                #pragma unroll
                for (int rr = 0; rr < 4; rr++)
                    TwS[(h * 64 + w * 16 + lq * 4 + rr) * 64 + nb * 16 + lm] = f2b(tacc[nb][rr]);
        }
    }
    __syncthreads();                                   // B4: Tw written
    const int qw = (w & 1) * 16 + lm;
    float rwc[2][8];
    #pragma unroll
    for (int h = 0; h < 2; h++)
        #pragma unroll
        for (int mb2 = 0; mb2 < 2; mb2++)
            #pragma unroll
            for (int rr = 0; rr < 4; rr++) {
                const int kw = mb2 * 16 + lq * 4 + rr;
                rwc[h][mb2 * 4 + rr] =
                    b2f(TwS[(h * 64 + w * 16 + lm) * 64 + qw - kw + 31]) - 16.0f;
            }

    // ones B-fragment for P row-sums on the MFMA pipe
    union { unsigned u[4]; bf16x8 v; } uo;
    uo.u[0] = uo.u[1] = uo.u[2] = uo.u[3] = 0x3F803F80u;
    const bf16x8 vone = uo.v;

    f32x4 lacc[2] = {};
    f32x4 oacc[2][4] = {};

    __syncthreads();                                   // B5: TwS readers done
    // prime tile 0 into buf 0
    #pragma unroll
    for (int c4 = 0; c4 < 2; c4++) {
        const int c = w * 2 + c4;
        const int row = c * 8 + srow;
        __builtin_amdgcn_global_load_lds(
            (gu32*)(kgb + row * 64 + sgcol), (lu32*)&ks2[c * 512], 16, 0, 0);
        __builtin_amdgcn_global_load_lds(
            (gu32*)(vgb + row * 64 + sgcol), (lu32*)&vsT[c * 512], 16, 0, 0);
    }

    #pragma unroll 1
    for (int kt = 0; kt < 16; kt++) {
        __syncthreads();           // buf[kt&1] DMA complete; its prior readers done
        const int bo = (kt & 1) * 4096;
        if (kt < 15) {             // issue DMA for kt+1 into the other buffer
            const int bn1 = ((kt + 1) & 1) * 4096;
            const u16* kp = kgb + (size_t)(kt + 1) * 4096;
            const u16* vp = vgb + (size_t)(kt + 1) * 4096;
            #pragma unroll
            for (int c4 = 0; c4 < 2; c4++) {
                const int c = w * 2 + c4;
                const int row = c * 8 + srow;
                __builtin_amdgcn_global_load_lds(
                    (gu32*)(kp + row * 64 + sgcol), (lu32*)&ks2[bn1 + c * 512], 16, 0, 0);
                __builtin_amdgcn_global_load_lds(
                    (gu32*)(vp + row * 64 + sgcol), (lu32*)&vsT[bn1 + c * 512], 16, 0, 0);
            }
        }
        // Th bias reads: col uniform per (h,w,kt); rows vary with lm (bank-clean)
        float rh[2][2];
        #pragma unroll
        for (int h = 0; h < 2; h++) {
            const int colp = h * 2 + whi - 2 * kt + 31;
            rh[h][0] = b2f(ThL[(h * 64 + w * 16 + lm) * 36 + colp]);
            rh[h][1] = b2f(ThL[(h * 64 + w * 16 + lm) * 36 + colp - 1]);
        }
        // K fragments once per round, shared by both halves
        bf16x8 ka0[4], ka1[4];
        #pragma unroll
        for (int mb = 0; mb < 4; mb++) {
            ka0[mb] = *(const bf16x8*)&ks2[bo + (mb * 16 + lm) * 64 + sw0];
            ka1[mb] = *(const bf16x8*)&ks2[bo + (mb * 16 + lm) * 64 + sw1];
        }
        #pragma unroll
        for (int h = 0; h < 2; h++) {
            f32x4 sacc[4];
            #pragma unroll
            for (int mb = 0; mb < 4; mb++) {
                #pragma unroll
                for (int j = 0; j < 4; j++)
                    sacc[mb][j] = rh[h][mb >> 1] + rwc[h][(mb & 1) * 4 + j];
                sacc[mb] = __builtin_amdgcn_mfma_f32_16x16x32_bf16(ka0[mb], bq0[h], sacc[mb], 0, 0, 0);
                sacc[mb] = __builtin_amdgcn_mfma_f32_16x16x32_bf16(ka1[mb], bq1[h], sacc[mb], 0, 0, 0);
            }
            #pragma unroll
            for (int mb = 0; mb < 4; mb++) {
                float p0 = exp2f(sacc[mb][0]);
                float p1 = exp2f(sacc[mb][1]);
                float p2 = exp2f(sacc[mb][2]);
                float p3 = exp2f(sacc[mb][3]);
                unsigned w0, w1;
                asm("v_cvt_pk_bf16_f32 %0, %1, %2" : "=v"(w0) : "v"(p0), "v"(p1));
                asm("v_cvt_pk_bf16_f32 %0, %1, %2" : "=v"(w1) : "v"(p2), "v"(p3));
                uint2 u; u.x = w0; u.y = w1;
                const int gg = 2 * mb + (lq >> 1);     // 16B group of col mb*16+lq*4
                *(uint2*)&ps[(w * 16 + lm) * 64 + ((gg ^ (lm & 7)) * 8) + (lq & 1) * 4] = u;
            }
            const bf16x8 pa0 = *(const bf16x8*)&ps[(w * 16 + lm) * 64 + sw0];
            const bf16x8 pa1 = *(const bf16x8*)&ps[(w * 16 + lm) * 64 + sw1];
            lacc[h] = __builtin_amdgcn_mfma_f32_16x16x32_bf16(pa0, vone, lacc[h], 0, 0, 0);
            lacc[h] = __builtin_amdgcn_mfma_f32_16x16x32_bf16(pa1, vone, lacc[h], 0, 0, 0);
            #pragma unroll
            for (int nb = 0; nb < 4; nb++) {
                bf16x8 vb0 = *(const bf16x8*)&vsT[bo + (nb * 16 + lm) * 64 + sw0];
                bf16x8 vb1 = *(const bf16x8*)&vsT[bo + (nb * 16 + lm) * 64 + sw1];
                oacc[h][nb] = __builtin_amdgcn_mfma_f32_16x16x32_bf16(pa0, vb0, oacc[h][nb], 0, 0, 0);
                oacc[h][nb] = __builtin_amdgcn_mfma_f32_16x16x32_bf16(pa1, vb1, oacc[h][nb], 0, 0, 0);
            }
        }
    }
    const int bb = bn / 12, nh = bn % 12;
    #pragma unroll
    for (int h = 0; h < 2; h++) {
        float rv[4];
        #pragma unroll
        for (int rr = 0; rr < 4; rr++) rv[rr] = 1.f / lacc[h][rr];
        #pragma unroll
        for (int nb = 0; nb < 4; nb++)
            #pragma unroll
            for (int rr = 0; rr < 4; rr++) {
                const int qrow = q0 + h * 64 + w * 16 + lq * 4 + rr;
                const int d = nb * 16 + lm;
                outb[((size_t)(bb * 1024 + qrow)) * 768 + nh * 64 + d] =
                    f2b(oacc[h][nb][rr] * rv[rr]);
            }
    }
}

// ---------------------------------------------------------------------------
extern "C" void kernel_launch(void* const* d_in, const int* in_sizes, int n_in,
                              void* d_out, int out_size, void* d_ws, size_t ws_size,
                              hipStream_t stream)
{
    u16* ws16  = (u16*)d_ws;
    u16* qkvT  = ws16;
    u16* xb    = ws16 + (size_t)18874368;
    u16* attn  = xb;                       // x dead after K1
    const size_t S = 25165824;
    u16* qkvw_b = ws16 + S;
    u16* projw_b = qkvw_b + 1769472;
    u16* qkvb_b = projw_b + 589824;
    u16* projb_b = qkvb_b + 2304;
    u16* relh_b = projb_b + 768;
    u16* relw_b = relh_b + 4032;
    int* flag = (int*)(ws16 + S + 2370432);

    detect_dtype<<<1, 64, 0, stream>>>((const u16*)d_in[0], flag);

    CvtArgs ca;
    ca.src[0] = d_in[0]; ca.dst[0] = xb;      ca.n[0] = 6291456; ca.sc[0] = 1.0f;
    ca.src[1] = d_in[1]; ca.dst[1] = qkvw_b;  ca.n[1] = 1769472; ca.sc[1] = 1.0f;
    ca.src[2] = d_in[3]; ca.dst[2] = projw_b; ca.n[2] = 589824;  ca.sc[2] = 1.0f;
    ca.src[3] = d_in[2]; ca.dst[3] = qkvb_b;  ca.n[3] = 2304;    ca.sc[3] = 1.0f;
    ca.src[4] = d_in[4]; ca.dst[4] = projb_b; ca.n[4] = 768;     ca.sc[4] = 1.0f;
    ca.src[5] = d_in[5]; ca.dst[5] = relh_b;  ca.n[5] = 4032;    ca.sc[5] = LOG2E;
    ca.src[6] = d_in[6]; ca.dst[6] = relw_b;  ca.n[6] = 4032;    ca.sc[6] = LOG2E;
    convert_all<<<2048, 256, 0, stream>>>(ca, flag);

    gemm128<1><<<dim3(64, 18), 256, 0, stream>>>(xb, qkvw_b, qkvb_b, nullptr, flag, qkvT, 2304, 768);
    flash_attn_mfma<<<dim3(96, 8), 256, 0, stream>>>(qkvT, relh_b, relw_b, attn);
    gemm128<0><<<dim3(64, 6), 256, 0, stream>>>(attn, projw_b, projb_b, d_out, flag, nullptr, 768, 768);
}

// Round 8
// 218.138 us; speedup vs baseline: 1.1396x; 1.0317x over previous
//
#include <hip/hip_runtime.h>

// R10: baseline 248.6us (flash 86.5, Occ 20.4%, 2 blk/CU).
// R11: flash LDS->49664, 3 blk/CU; cvt_pk; lsum on MFMA. 233.7 (flash 72.4).
// R12: flash QBLK=128, 768 blocks = 3/CU exactly; K frags shared by halves.
// R15: qkv rope trig table (bit-identical). R16 resubmits (broker timeouts).
// R17 measured R12+R15: 225.1us, absmax unchanged. qkv gemm now #1 (63.4us,
//      Mfma 17.7, VALU 21.8, HBM 13.7%, Occ 16.7 -> latency-bound: K-loop is
//      issue->drain->compute with NO prefetch overlap; every iter pays full
//      mem latency with all waves at the barrier).
// R18: gemm128 K-loop -> flash-style double buffer at BK=32: two 16KB
//      tile-pairs fit the SAME 32KB smem (ct still aliases; LDS 36864, 4
//      blk/CU kept) while DMA for tile k+1 flies during tile k's compute.
//      One barrier/iter (24 total = unchanged). New conflict-free swizzle for
//      32-col rows: DMA src colgroup (l&3)^((l>>2)&3); read (lq^(lm&3))*8.
//      Epilogues untouched. Applies to qkv AND proj.

typedef unsigned short u16;
typedef __attribute__((ext_vector_type(8))) __bf16 bf16x8;
typedef __attribute__((ext_vector_type(4))) float f32x4;
typedef __attribute__((address_space(1))) const unsigned int gu32;
typedef __attribute__((address_space(3))) unsigned int lu32;

#define LOG2E 1.4426950408889634f

__device__ __forceinline__ float b2f(u16 u) {
    unsigned int i = ((unsigned int)u) << 16;
    float f; __builtin_memcpy(&f, &i, 4); return f;
}
__device__ __forceinline__ u16 f2b(float f) {
    unsigned int x; __builtin_memcpy(&x, &f, 4);
    x += 0x7fffu + ((x >> 16) & 1u);   // RTNE
    return (u16)(x >> 16);
}

// ---------------------------------------------------------------------------
__global__ void detect_dtype(const u16* __restrict__ x, int* __restrict__ flag)
{
    if (threadIdx.x == 0 && blockIdx.x == 0) {
        float mx = 0.f;
        for (int i = 0; i < 128; i++) {
            float v = fabsf(b2f(x[i]));
            if (!(v <= 1e30f)) v = 1e30f;
            mx = fmaxf(mx, v);
        }
        *flag = (mx > 1e4f) ? 1 : 0;
    }
}

struct CvtArgs {
    const void* src[7];
    u16*        dst[7];
    int         n[7];
    float       sc[7];
};

__global__ __launch_bounds__(256) void convert_all(CvtArgs a, const int* __restrict__ flag)
{
    const int fl = *flag;
    const int g = blockIdx.x * 256 + threadIdx.x;
    const int stride = gridDim.x * 256;
    #pragma unroll 1
    for (int s = 0; s < 7; s++) {
        const int n = a.n[s];
        const float sc = a.sc[s];
        const float* fs = (const float*)a.src[s];
        const u16*  hs = (const u16*)a.src[s];
        u16* d = a.dst[s];
        for (int i = g; i < n; i += stride) {
            float v = fl ? fs[i] : b2f(hs[i]);
            d[i] = f2b(v * sc);
        }
    }
}

// ---------------------------------------------------------------------------
// 128x128 GEMM (TN), BK=32 double-buffered global_load_lds staging (DMA for
// tile k+1 in flight during tile k's compute; one barrier/iter).
// EPI=0: proj (dual-dtype store). EPI=1: qkv (rope via LDS trig table;
// LDS-staged stores; V -> [bn][kt][d][l64] tile-contiguous).
// ---------------------------------------------------------------------------
template <int EPI>
__global__ __launch_bounds__(256) void gemm128(
    const u16* __restrict__ A, const u16* __restrict__ Bw,
    const u16* __restrict__ bias, void* __restrict__ Cout,
    const int* __restrict__ flag, u16* __restrict__ qkvT, int N, int K)
{
    __shared__ __align__(16) u16 smem[16384];    // [lA0|lB0|lA1|lB1] 4x8KB; ct aliases
    __shared__ float tabc[512];                  // rope cos table [coord][jj] (EPI==1)
    __shared__ float tabs[512];                  // rope sin table
    u16* ct = smem;
    const int tid = threadIdx.x;
    const int m0 = blockIdx.x * 128, n0 = blockIdx.y * 128;
    const int wave = tid >> 6, lane = tid & 63;
    const int wm = (wave & 1) * 64, wn = (wave >> 1) * 64;
    const int lm = lane & 15, lq = lane >> 4;
    // BK=32 staging: per DMA inst a wave covers 16 rows x 64B.
    const int qr  = lane >> 2;                     // row within 16-row chunk
    const int scg = ((lane & 3) ^ (qr & 3)) * 8;   // swizzled global colgroup (u16)
    const int rsw = (lq ^ (lm & 3)) * 8;           // frag read col offset (u16)

    if (EPI == 1) {
        // 512 entries, 2/thread; same __expf/__sincosf as the original
        // per-element path -> bit-identical values.
        #pragma unroll
        for (int e = tid; e < 512; e += 256) {
            const int coord = e >> 4, jj = e & 15;
            const float ang = (float)coord * __expf(-(float)jj * 0.5756462732485115f);
            float sn, cs; __sincosf(ang, &sn, &cs);
            tabc[e] = cs; tabs[e] = sn;
        }
    }

    const int nkt = K >> 5;
    // prologue: DMA tile 0 -> buf 0
    #pragma unroll
    for (int c4 = 0; c4 < 2; c4++) {
        const int c = wave * 2 + c4;
        const int row = c * 16 + qr;
        __builtin_amdgcn_global_load_lds(
            (gu32*)(A + (size_t)(m0 + row) * K + scg),
            (lu32*)&smem[c * 512], 16, 0, 0);
        __builtin_amdgcn_global_load_lds(
            (gu32*)(Bw + (size_t)(n0 + row) * K + scg),
            (lu32*)&smem[4096 + c * 512], 16, 0, 0);
    }

    f32x4 acc[4][4] = {};
    #pragma unroll 1
    for (int kt = 0; kt < nkt; kt++) {
        __syncthreads();               // buf[kt&1] DMA complete; prior readers done
        const int bo = (kt & 1) * 8192;
        if (kt + 1 < nkt) {            // issue DMA for kt+1 into the other buffer
            const int bn1 = ((kt + 1) & 1) * 8192;
            const int k1 = (kt + 1) * 32;
            #pragma unroll
            for (int c4 = 0; c4 < 2; c4++) {
                const int c = wave * 2 + c4;
                const int row = c * 16 + qr;
                __builtin_amdgcn_global_load_lds(
                    (gu32*)(A + (size_t)(m0 + row) * K + k1 + scg),
                    (lu32*)&smem[bn1 + c * 512], 16, 0, 0);
                __builtin_amdgcn_global_load_lds(
                    (gu32*)(Bw + (size_t)(n0 + row) * K + k1 + scg),
                    (lu32*)&smem[bn1 + 4096 + c * 512], 16, 0, 0);
            }
        }
        bf16x8 af[4], bfr[4];
        #pragma unroll
        for (int i = 0; i < 4; i++) af[i]  = *(const bf16x8*)&smem[bo + (wm + i * 16 + lm) * 32 + rsw];
        #pragma unroll
        for (int j = 0; j < 4; j++) bfr[j] = *(const bf16x8*)&smem[bo + 4096 + (wn + j * 16 + lm) * 32 + rsw];
        #pragma unroll
        for (int i = 0; i < 4; i++)
            #pragma unroll
            for (int j = 0; j < 4; j++)
                acc[i][j] = __builtin_amdgcn_mfma_f32_16x16x32_bf16(af[i], bfr[j], acc[i][j], 0, 0, 0);
    }

    if (EPI == 0) {
        const int fl = *flag;
        #pragma unroll
        for (int j = 0; j < 4; j++) {
            const int n = n0 + wn + j * 16 + lm;
            const float bj = b2f(bias[n]);
            #pragma unroll
            for (int i = 0; i < 4; i++)
                #pragma unroll
                for (int r = 0; r < 4; r++) {
                    const int m = m0 + wm + i * 16 + lq * 4 + r;
                    const float v = acc[i][j][r] + bj;
                    if (fl) ((float*)Cout)[(size_t)m * 768 + n] = v;
                    else    ((u16*)Cout)[(size_t)m * 768 + n] = f2b(v);
                }
        }
    } else {
        const int which = n0 / 768;
        const bool vt = (which == 2);
        __syncthreads();               // all buf readers done; ct may overwrite
        #pragma unroll
        for (int j = 0; j < 4; j++) {
            const int nl = wn + j * 16 + lm;
            const int n = n0 + nl;
            const float bj = b2f(bias[n]);
            const int d = n & 63;
            const int pi = d >> 1;
            const int jj = pi & 15;
            #pragma unroll
            for (int i = 0; i < 4; i++)
                #pragma unroll
                for (int r = 0; r < 4; r++) {
                    const int ml = wm + i * 16 + lq * 4 + r;
                    const int m = m0 + ml;
                    float v = acc[i][j][r] + bj;
                    const float p = __shfl_xor(v, 1);
                    const int l = m & 1023;
                    float o = v;
                    if (which < 2) {
                        const int coord = (pi < 16) ? (l & 31) : (l >> 5);
                        const float cs = tabc[coord * 16 + jj];
                        const float sn = tabs[coord * 16 + jj];
                        o = v * cs + ((d & 1) ? p * sn : -(p * sn));
                        if (which == 1) o *= 0.125f * LOG2E;
                    }
                    ct[vt ? nl * 128 + ml : ml * 128 + nl] = f2b(o);
                }
        }
        __syncthreads();
        const size_t HL = (size_t)96 * 1024 * 64;
        const int nh0 = (n0 >> 6) % 12, bb = m0 >> 10, l0 = m0 & 1023;
        if (!vt) {
            #pragma unroll
            for (int pass = 0; pass < 8; pass++) {
                const int chunk = pass * 256 + tid;
                const int run = chunk >> 3, lc = chunk & 7;
                const int ml = run >> 1, h = run & 1;
                u16* gp = qkvT + (size_t)which * HL
                        + ((size_t)(bb * 12 + nh0 + h) * 1024 + l0 + ml) * 64 + lc * 8;
                *(uint4*)gp = *(const uint4*)&ct[ml * 128 + h * 64 + lc * 8];
            }
        } else {
            const int kt0 = l0 >> 6;
            #pragma unroll
            for (int pass = 0; pass < 8; pass++) {
                const int run = pass * 16 + (tid >> 4);
                const int ln = tid & 15;
                const int half = ln >> 3, l8 = ln & 7;
                u16* gp = qkvT + 2 * HL
                        + (size_t)(bb * 12 + nh0 + (run >> 6)) * 65536
                        + (size_t)(kt0 + half) * 4096 + (run & 63) * 64 + l8 * 8;
                *(uint4*)gp = *(const uint4*)&ct[run * 128 + ln * 8];
            }
        }
    }
}

// ---------------------------------------------------------------------------
// K2: MFMA flash attention, QBLK=128 (2 Q-halves per block), KVBLK=64.
// 50176B LDS -> 3 blocks/CU; 768 blocks = exactly 3/CU (no tail).
// K frags read once/round, reused by both halves; bias in sacc init.
// ---------------------------------------------------------------------------
__global__ __launch_bounds__(256, 3) void flash_attn_mfma(
    const u16* __restrict__ qkvT, const u16* __restrict__ relH,
    const u16* __restrict__ relW, u16* __restrict__ outb)
{
    __shared__ __align__(16) u16 ks2[2 * 4096];    // K dbuf (swz); prologue: Tw scratch [128][64]
    __shared__ __align__(16) u16 vsT[2 * 4096];    // V dbuf (swz); prologue: rel staging (buf0)
    __shared__ __align__(16) u16 ps[4096];         // P tile (swz), halves sequential
    __shared__ __align__(16) u16 ThL[128 * 36];    // Th col-window [qh0, qh0+34]
    u16* rel = vsT;
    u16* TwS = ks2;                                // [128][64] scratch, freed before DMA

    const int tid = threadIdx.x;
    const int w = tid >> 6, lane = tid & 63;
    const int lm = lane & 15, lq = lane >> 4;
    const int whi = (w >= 2) ? 1 : 0;
    const int srow = lane >> 3;
    const int sgcol = ((lane & 7) ^ (srow & 7)) * 8;   // swizzled global col
    const int sw0 = (lq ^ (lm & 7)) * 8;
    const int sw1 = ((lq + 4) ^ (lm & 7)) * 8;

    const int bn = blockIdx.x, q0 = blockIdx.y * 128;
    const int qh0 = blockIdx.y * 4;                // q0 >> 5
    const size_t HL = (size_t)96 * 1024 * 64;
    const u16* qg  = qkvT + (size_t)bn * 65536 + (size_t)q0 * 64;
    const u16* kgb = qkvT + HL + (size_t)bn * 65536;
    const u16* vgb = qkvT + 2 * HL + (size_t)bn * 65536;   // [kt][d][l64]

    // Q fragments: direct global -> registers (once per block)
    bf16x8 bq0[2], bq1[2];
    #pragma unroll
    for (int h = 0; h < 2; h++) {
        const u16* qr2 = qg + (h * 64 + w * 16 + lm) * 64;
        bq0[h] = *(const bf16x8*)(qr2 + lq * 8);
        bq1[h] = *(const bf16x8*)(qr2 + 32 + lq * 8);
    }

    // relH -> rel (vsT buf0, unswizzled [64][64])
    for (int g = tid; g < 1008; g += 256) {
        int r = g >> 4, c = (g & 15) * 4;
        *(ushort4*)&rel[r * 64 + c] = *(const ushort4*)(relH + g * 4);
    }
    if (tid < 16) { ushort4 z = {0, 0, 0, 0}; *(ushort4*)&rel[63 * 64 + tid * 4] = z; }
    __syncthreads();                                   // B1

    {   // Th = Q . relH^T -> ThL window [128][36]
        #pragma unroll
        for (int h = 0; h < 2; h++) {
            f32x4 tacc[4] = {};
            #pragma unroll
            for (int nb = 0; nb < 4; nb++) {
                bf16x8 r0 = *(const bf16x8*)&rel[(nb * 16 + lm) * 64 + lq * 8];
                bf16x8 r1 = *(const bf16x8*)&rel[(nb * 16 + lm) * 64 + 32 + lq * 8];
                tacc[nb] = __builtin_amdgcn_mfma_f32_16x16x32_bf16(bq0[h], r0, tacc[nb], 0, 0, 0);
                tacc[nb] = __builtin_amdgcn_mfma_f32_16x16x32_bf16(bq1[h], r1, tacc[nb], 0, 0, 0);
            }
            #pragma unroll
            for (int nb = 0; nb < 4; nb++)
                #pragma unroll
                for (int rr = 0; rr < 4; rr++) {
                    const unsigned cw = (unsigned)(nb * 16 + lm - qh0);
                    if (cw < 36u)
                        ThL[(h * 64 + w * 16 + lq * 4 + rr) * 36 + cw] = f2b(tacc[nb][rr]);
                }
        }
    }
    __syncthreads();                                   // B2: relH reads done
    for (int g = tid; g < 1008; g += 256) {
        int r = g >> 4, c = (g & 15) * 4;
        *(ushort4*)&rel[r * 64 + c] = *(const ushort4*)(relW + g * 4);
    }
    if (tid < 16) { ushort4 z = {0, 0, 0, 0}; *(ushort4*)&rel[63 * 64 + tid * 4] = z; }
    __syncthreads();                                   // B3: relW staged
    {   // Tw = Q . relW^T -> TwS [128][64]
        #pragma unroll
        for (int h = 0; h < 2; h++) {
            f32x4 tacc[4] = {};
            #pragma unroll
            for (int nb = 0; nb < 4; nb++) {
                bf16x8 r0 = *(const bf16x8*)&rel[(nb * 16 + lm) * 64 + lq * 8];
                bf16x8 r1 = *(const bf16x8*)&rel[(nb * 16 + lm) * 64 + 32 + lq * 8];
                tacc[nb] = __builtin_amdgcn_mfma_f32_16x16x32_bf16(bq0[h], r0, tacc[nb], 0, 0, 0);
                tacc[nb] = __builtin_amdgcn_mfma_f32_16x16x32_bf16(bq1[h], r1, tacc[nb], 0, 0, 0);
            }
            #pragma unroll
            for (int nb = 0; nb < 4; nb++)
                #pragma unroll
                for (int rr = 0; rr < 4; rr++)
                    TwS[(h * 64 + w * 16 + lq * 4 + rr) * 64 + nb * 16 + lm] = f2b(tacc[nb][rr]);
        }
    }
    __syncthreads();                                   // B4: Tw written
    const int qw = (w & 1) * 16 + lm;
    float rwc[2][8];
    #pragma unroll
    for (int h = 0; h < 2; h++)
        #pragma unroll
        for (int mb2 = 0; mb2 < 2; mb2++)
            #pragma unroll
            for (int rr = 0; rr < 4; rr++) {
                const int kw = mb2 * 16 + lq * 4 + rr;
                rwc[h][mb2 * 4 + rr] =
                    b2f(TwS[(h * 64 + w * 16 + lm) * 64 + qw - kw + 31]) - 16.0f;
            }

    // ones B-fragment for P row-sums on the MFMA pipe
    union { unsigned u[4]; bf16x8 v; } uo;
    uo.u[0] = uo.u[1] = uo.u[2] = uo.u[3] = 0x3F803F80u;
    const bf16x8 vone = uo.v;

    f32x4 lacc[2] = {};
    f32x4 oacc[2][4] = {};

    __syncthreads();                                   // B5: TwS readers done
    // prime tile 0 into buf 0
    #pragma unroll
    for (int c4 = 0; c4 < 2; c4++) {
        const int c = w * 2 + c4;
        const int row = c * 8 + srow;
        __builtin_amdgcn_global_load_lds(
            (gu32*)(kgb + row * 64 + sgcol), (lu32*)&ks2[c * 512], 16, 0, 0);
        __builtin_amdgcn_global_load_lds(
            (gu32*)(vgb + row * 64 + sgcol), (lu32*)&vsT[c * 512], 16, 0, 0);
    }

    #pragma unroll 1
    for (int kt = 0; kt < 16; kt++) {
        __syncthreads();           // buf[kt&1] DMA complete; its prior readers done
        const int bo = (kt & 1) * 4096;
        if (kt < 15) {             // issue DMA for kt+1 into the other buffer
            const int bn1 = ((kt + 1) & 1) * 4096;
            const u16* kp = kgb + (size_t)(kt + 1) * 4096;
            const u16* vp = vgb + (size_t)(kt + 1) * 4096;
            #pragma unroll
            for (int c4 = 0; c4 < 2; c4++) {
                const int c = w * 2 + c4;
                const int row = c * 8 + srow;
                __builtin_amdgcn_global_load_lds(
                    (gu32*)(kp + row * 64 + sgcol), (lu32*)&ks2[bn1 + c * 512], 16, 0, 0);
                __builtin_amdgcn_global_load_lds(
                    (gu32*)(vp + row * 64 + sgcol), (lu32*)&vsT[bn1 + c * 512], 16, 0, 0);
            }
        }
        // Th bias reads: col uniform per (h,w,kt); rows vary with lm (bank-clean)
        float rh[2][2];
        #pragma unroll
        for (int h = 0; h < 2; h++) {
            const int colp = h * 2 + whi - 2 * kt + 31;
            rh[h][0] = b2f(ThL[(h * 64 + w * 16 + lm) * 36 + colp]);
            rh[h][1] = b2f(ThL[(h * 64 + w * 16 + lm) * 36 + colp - 1]);
        }
        // K fragments once per round, shared by both halves
        bf16x8 ka0[4], ka1[4];
        #pragma unroll
        for (int mb = 0; mb < 4; mb++) {
            ka0[mb] = *(const bf16x8*)&ks2[bo + (mb * 16 + lm) * 64 + sw0];
            ka1[mb] = *(const bf16x8*)&ks2[bo + (mb * 16 + lm) * 64 + sw1];
        }
        #pragma unroll
        for (int h = 0; h < 2; h++) {
            f32x4 sacc[4];
            #pragma unroll
            for (int mb = 0; mb < 4; mb++) {
                #pragma unroll
                for (int j = 0; j < 4; j++)
                    sacc[mb][j] = rh[h][mb >> 1] + rwc[h][(mb & 1) * 4 + j];
                sacc[mb] = __builtin_amdgcn_mfma_f32_16x16x32_bf16(ka0[mb], bq0[h], sacc[mb], 0, 0, 0);
                sacc[mb] = __builtin_amdgcn_mfma_f32_16x16x32_bf16(ka1[mb], bq1[h], sacc[mb], 0, 0, 0);
            }
            #pragma unroll
            for (int mb = 0; mb < 4; mb++) {
                float p0 = exp2f(sacc[mb][0]);
                float p1 = exp2f(sacc[mb][1]);
                float p2 = exp2f(sacc[mb][2]);
                float p3 = exp2f(sacc[mb][3]);
                unsigned w0, w1;
                asm("v_cvt_pk_bf16_f32 %0, %1, %2" : "=v"(w0) : "v"(p0), "v"(p1));
                asm("v_cvt_pk_bf16_f32 %0, %1, %2" : "=v"(w1) : "v"(p2), "v"(p3));
                uint2 u; u.x = w0; u.y = w1;
                const int gg = 2 * mb + (lq >> 1);     // 16B group of col mb*16+lq*4
                *(uint2*)&ps[(w * 16 + lm) * 64 + ((gg ^ (lm & 7)) * 8) + (lq & 1) * 4] = u;
            }
            const bf16x8 pa0 = *(const bf16x8*)&ps[(w * 16 + lm) * 64 + sw0];
            const bf16x8 pa1 = *(const bf16x8*)&ps[(w * 16 + lm) * 64 + sw1];
            lacc[h] = __builtin_amdgcn_mfma_f32_16x16x32_bf16(pa0, vone, lacc[h], 0, 0, 0);
            lacc[h] = __builtin_amdgcn_mfma_f32_16x16x32_bf16(pa1, vone, lacc[h], 0, 0, 0);
            #pragma unroll
            for (int nb = 0; nb < 4; nb++) {
                bf16x8 vb0 = *(const bf16x8*)&vsT[bo + (nb * 16 + lm) * 64 + sw0];
                bf16x8 vb1 = *(const bf16x8*)&vsT[bo + (nb * 16 + lm) * 64 + sw1];
                oacc[h][nb] = __builtin_amdgcn_mfma_f32_16x16x32_bf16(pa0, vb0, oacc[h][nb], 0, 0, 0);
                oacc[h][nb] = __builtin_amdgcn_mfma_f32_16x16x32_bf16(pa1, vb1, oacc[h][nb], 0, 0, 0);
            }
        }
    }
    const int bb = bn / 12, nh = bn % 12;
    #pragma unroll
    for (int h = 0; h < 2; h++) {
        float rv[4];
        #pragma unroll
        for (int rr = 0; rr < 4; rr++) rv[rr] = 1.f / lacc[h][rr];
        #pragma unroll
        for (int nb = 0; nb < 4; nb++)
            #pragma unroll
            for (int rr = 0; rr < 4; rr++) {
                const int qrow = q0 + h * 64 + w * 16 + lq * 4 + rr;
                const int d = nb * 16 + lm;
                outb[((size_t)(bb * 1024 + qrow)) * 768 + nh * 64 + d] =
                    f2b(oacc[h][nb][rr] * rv[rr]);
            }
    }
}

// ---------------------------------------------------------------------------
extern "C" void kernel_launch(void* const* d_in, const int* in_sizes, int n_in,
                              void* d_out, int out_size, void* d_ws, size_t ws_size,
                              hipStream_t stream)
{
    u16* ws16  = (u16*)d_ws;
    u16* qkvT  = ws16;
    u16* xb    = ws16 + (size_t)18874368;
    u16* attn  = xb;                       // x dead after K1
    const size_t S = 25165824;
    u16* qkvw_b = ws16 + S;
    u16* projw_b = qkvw_b + 1769472;
    u16* qkvb_b = projw_b + 589824;
    u16* projb_b = qkvb_b + 2304;
    u16* relh_b = projb_b + 768;
    u16* relw_b = relh_b + 4032;
    int* flag = (int*)(ws16 + S + 2370432);

    detect_dtype<<<1, 64, 0, stream>>>((const u16*)d_in[0], flag);

    CvtArgs ca;
    ca.src[0] = d_in[0]; ca.dst[0] = xb;      ca.n[0] = 6291456; ca.sc[0] = 1.0f;
    ca.src[1] = d_in[1]; ca.dst[1] = qkvw_b;  ca.n[1] = 1769472; ca.sc[1] = 1.0f;
    ca.src[2] = d_in[3]; ca.dst[2] = projw_b; ca.n[2] = 589824;  ca.sc[2] = 1.0f;
    ca.src[3] = d_in[2]; ca.dst[3] = qkvb_b;  ca.n[3] = 2304;    ca.sc[3] = 1.0f;
    ca.src[4] = d_in[4]; ca.dst[4] = projb_b; ca.n[4] = 768;     ca.sc[4] = 1.0f;
    ca.src[5] = d_in[5]; ca.dst[5] = relh_b;  ca.n[5] = 4032;    ca.sc[5] = LOG2E;
    ca.src[6] = d_in[6]; ca.dst[6] = relw_b;  ca.n[6] = 4032;    ca.sc[6] = LOG2E;
    convert_all<<<2048, 256, 0, stream>>>(ca, flag);

    gemm128<1><<<dim3(64, 18), 256, 0, stream>>>(xb, qkvw_b, qkvb_b, nullptr, flag, qkvT, 2304, 768);
    flash_attn_mfma<<<dim3(96, 8), 256, 0, stream>>>(qkvT, relh_b, relw_b, attn);
    gemm128<0><<<dim3(64, 6), 256, 0, stream>>>(attn, projw_b, projb_b, d_out, flag, nullptr, 768, 768);
}